// Round 7
// baseline (230.137 us; speedup 1.0000x reference)
//
#include <hip/hip_runtime.h>
#include <hip/hip_bf16.h>

// LinearAttention (efficient attention): B=4 N=4096 D_MODEL=1024 H=16 DH=64
// Pipeline: cvt -> GEMM1(qkv, 256^2 ring-pipelined) -> ksoftmax stats
//           -> context(K^T V, +p2 fused) -> attn GEMM (q-softmax fused)
//           -> final GEMM (256^2, +bias, f32)

typedef unsigned short u16t;
typedef __bf16 bf16x8 __attribute__((ext_vector_type(8)));
typedef float f32x4 __attribute__((ext_vector_type(4)));
typedef unsigned short ushort8 __attribute__((ext_vector_type(8)));

__device__ __forceinline__ u16t f2bf(float f) {
    union { float f; unsigned int u; } v; v.f = f;
    unsigned int r = v.u + 0x7fffu + ((v.u >> 16) & 1u);
    return (u16t)(r >> 16);
}
__device__ __forceinline__ float bf2f(u16t h) {
    union { unsigned int u; float f; } v; v.u = ((unsigned int)h) << 16;
    return v.f;
}

#define GLOAD_LDS16(gptr, lptr) \
    __builtin_amdgcn_global_load_lds((const __attribute__((address_space(1))) unsigned int*)(gptr), \
                                     (__attribute__((address_space(3))) unsigned int*)(lptr), 16, 0, 0)
#define SFENCE asm volatile("" ::: "memory")

// ---------------- conversion kernels ----------------

__global__ void cvt_f32_bf16(const float* __restrict__ in, u16t* __restrict__ out, int n) {
    int i = (blockIdx.x * blockDim.x + threadIdx.x) * 4;
    int stride = gridDim.x * blockDim.x * 4;
    for (; i < n; i += stride) {
        float4 v = *(const float4*)(in + i);
        ushort4 o;
        o.x = f2bf(v.x); o.y = f2bf(v.y); o.z = f2bf(v.z); o.w = f2bf(v.w);
        *(ushort4*)(out + i) = o;
    }
}

// in [R][C] f32 -> out [C][R] bf16 (transpose + convert). grid (C/32, R/32), block (32,8)
__global__ void transpose_cvt(const float* __restrict__ in, u16t* __restrict__ out, int R, int C) {
    __shared__ float tile[32][33];
    int c0 = blockIdx.x * 32, r0 = blockIdx.y * 32;
    int tx = threadIdx.x, ty = threadIdx.y;
    for (int i = 0; i < 32; i += 8)
        tile[ty + i][tx] = in[(size_t)(r0 + ty + i) * C + c0 + tx];
    __syncthreads();
    for (int i = 0; i < 32; i += 8)
        out[(size_t)(c0 + ty + i) * R + r0 + tx] = f2bf(tile[tx][ty + i]);
}

// ---------------- 256x256 ring-pipelined bf16 GEMM: C = A * Bt^T ----------------
// A [M][K] bf16 row-major, Bt [N][K] bf16 row-major (pre-transposed B).
// 512 threads = 8 waves (2 M x 4 N), per-wave output 128x64, BK=64, LDS 128KB dbuf.
//
// LDS per buffer (u16 units): A groups g=0..3 at g*4096 (group g = global rows
// m0+32g+rr, +96 if rr>=32; phase q reads group q). B at 16384: half h at h*8192.
// T2 swizzle: col-chunk stored XOR (row&7); staged via inverse-permuted global source
// (verified r3: SQ_LDS_BANK_CONFLICT == 0).
//
// Ring pipeline (m201 reconstruction): 4 phases/tile, each
//   {reads (ph1: 8 B frags held all tile + 4 A-g0; else 4 A frags) | stage ONE
//    half-tile | barrier | setprio 16 MFMA (C-quadrant q)}.
// Stage ring: ph1->A-h1(kt+1)[p^1 g23], ph2->B-h0(kt+1), ph3->B-h1(kt+1),
// ph4->A-h0(kt+2) into CURRENT buf g01 (dead since ph2). Phase barriers are the
// ring free-gates (slot staged only after the barrier following its last reader).
// ONE counted vmcnt(2) per tile at ph4 (in-order queue audit: keeps only
// A-h0(kt+2) outstanding; everything ph1 of kt+1 reads has landed). Tail:
// kt==NT-2 -> vmcnt(0); kt==NT-1 -> none. Prologue stages 5 half-tiles
// {Ah0(0),Ah1(0),Bh0(0),Bh1(0),Ah0(1)} then vmcnt(2) -> steady state.
template<int OUTF32, int BIAS>
__global__ __launch_bounds__(512, 2) void gemm256(const u16t* __restrict__ A, const u16t* __restrict__ Bt,
                                                  void* __restrict__ Cout, const float* __restrict__ bias,
                                                  int M, int N, int K, int NBX) {
    __shared__ __align__(16) u16t lds[65536];   // 128 KB
    const int t = threadIdx.x;
    const int l = t & 63, w = t >> 6;
    const int wm = w >> 2, wn = w & 3;

    // XCD-aware bijective swizzle (gridDim.x % 8 == 0)
    int cpx = gridDim.x >> 3;
    int wg = ((int)blockIdx.x & 7) * cpx + ((int)blockIdx.x >> 3);
    int bx = wg % NBX, by = wg / NBX;
    const int m0 = by * 256, n0 = bx * 256;
    const int NT = K >> 6;

    // fragment read addressing (u16 units, swizzle folded)
    const int colk0 = ((l >> 4) ^ (l & 7)) * 8;
    const int colk1 = colk0 ^ 32;
    const int abase = (wm * 32 + (l & 15)) * 64;                       // within A group
    const int bbase = 16384 + (wn >> 1) * 8192 + ((wn & 1) * 64 + (l & 15)) * 64;

    // staging addressing
    const int rr = w * 8 + (l >> 3);                                   // row within 64-row group
    const int coloff = ((l ^ (l >> 3)) & 7) * 8;                       // inverse swizzle on source
    const int rowA = rr + ((rr >= 32) ? 96 : 0);                       // A group-local -> global offset
    const u16t* pa_st = A  + (size_t)(m0 + rowA) * K + coloff;
    const u16t* pb_st = Bt + (size_t)(n0 + rr) * K + coloff;
    const int so = w * 512;

// half-tile stages (2 gload_lds each): hh: 0=Bh0 1=Bh1 2=Ah0(g01) 3=Ah1(g23)
#define SPAIR(hh, kto, pb) do { \
    size_t k64_ = (size_t)(kto) * 64; \
    if ((hh) == 0) { \
        GLOAD_LDS16(pb_st + k64_,                  &lds[(pb) * 32768 + 16384 + so]); \
        GLOAD_LDS16(pb_st + k64_ + (size_t)64 * K, &lds[(pb) * 32768 + 20480 + so]); \
    } else if ((hh) == 1) { \
        GLOAD_LDS16(pb_st + k64_ + (size_t)128 * K, &lds[(pb) * 32768 + 24576 + so]); \
        GLOAD_LDS16(pb_st + k64_ + (size_t)192 * K, &lds[(pb) * 32768 + 28672 + so]); \
    } else if ((hh) == 2) { \
        GLOAD_LDS16(pa_st + k64_,                  &lds[(pb) * 32768 + so]); \
        GLOAD_LDS16(pa_st + k64_ + (size_t)32 * K, &lds[(pb) * 32768 + 4096 + so]); \
    } else { \
        GLOAD_LDS16(pa_st + k64_ + (size_t)64 * K, &lds[(pb) * 32768 + 8192 + so]); \
        GLOAD_LDS16(pa_st + k64_ + (size_t)96 * K, &lds[(pb) * 32768 + 12288 + so]); \
    } \
} while (0)

    f32x4 acc[8][4] = {};

    // prologue: Ah0(0), Ah1(0), Bh0(0), Bh1(0), Ah0(1) -> counted wait
    SPAIR(2, 0, 0); SFENCE;
    SPAIR(3, 0, 0); SFENCE;
    SPAIR(0, 0, 0); SFENCE;
    SPAIR(1, 0, 0); SFENCE;
    SPAIR(2, 1, 1); SFENCE;
    asm volatile("s_waitcnt vmcnt(2)" ::: "memory");
    __builtin_amdgcn_s_barrier();

    for (int kt = 0; kt < NT; ++kt) {
        const int p = kt & 1;
        const u16t* lA = &lds[p * 32768];
        bf16x8 bfr[4][2];
#pragma unroll
        for (int q = 0; q < 4; ++q) {
            // ---- reads ----
            if (q == 0) {
#pragma unroll
                for (int ni = 0; ni < 4; ++ni) {
                    bfr[ni][0] = *(const bf16x8*)&lA[bbase + ni * 1024 + colk0];
                    bfr[ni][1] = *(const bf16x8*)&lA[bbase + ni * 1024 + colk1];
                }
            }
            bf16x8 af[2][2];
            af[0][0] = *(const bf16x8*)&lA[q * 4096 + abase + colk0];
            af[0][1] = *(const bf16x8*)&lA[q * 4096 + abase + colk1];
            af[1][0] = *(const bf16x8*)&lA[q * 4096 + abase + 1024 + colk0];
            af[1][1] = *(const bf16x8*)&lA[q * 4096 + abase + 1024 + colk1];
            // ---- ring stage (one half-tile per phase) ----
            if (q == 0) { if (kt + 1 < NT) SPAIR(3, kt + 1, p ^ 1); }      // A-h1(kt+1)
            else if (q == 1) { if (kt + 1 < NT) SPAIR(0, kt + 1, p ^ 1); } // B-h0(kt+1)
            else if (q == 2) { if (kt + 1 < NT) SPAIR(1, kt + 1, p ^ 1); } // B-h1(kt+1)
            else { if (kt + 2 < NT) SPAIR(2, kt + 2, p); }                 // A-h0(kt+2) -> cur buf g01
            SFENCE;
            // ---- single counted wait per tile ----
            if (q == 3) {
                if (kt < NT - 2)       asm volatile("s_waitcnt vmcnt(2)" ::: "memory");
                else if (kt == NT - 2) asm volatile("s_waitcnt vmcnt(0)" ::: "memory");
            }
            __builtin_amdgcn_s_barrier();
            // ---- 16 MFMA: C-quadrant q ----
            __builtin_amdgcn_s_setprio(1);
#pragma unroll
            for (int dm = 0; dm < 2; ++dm)
#pragma unroll
                for (int ni = 0; ni < 4; ++ni)
#pragma unroll
                    for (int kk = 0; kk < 2; ++kk)
                        acc[q * 2 + dm][ni] = __builtin_amdgcn_mfma_f32_16x16x32_bf16(
                            af[dm][kk], bfr[ni][kk], acc[q * 2 + dm][ni], 0, 0, 0);
            __builtin_amdgcn_s_setprio(0);
        }
    }
#undef SPAIR

    // epilogue
#pragma unroll
    for (int mi = 0; mi < 8; ++mi) {
        int row = m0 + wm * 128 + mi * 16 + ((l >> 4) << 2);
#pragma unroll
        for (int ni = 0; ni < 4; ++ni) {
            int col = n0 + wn * 64 + ni * 16 + (l & 15);
            float bv = BIAS ? bias[col] : 0.f;
#pragma unroll
            for (int j = 0; j < 4; ++j) {
                float v = acc[mi][ni][j] + bv;
                if (OUTF32) ((float*)Cout)[(size_t)(row + j) * N + col] = v;
                else        ((u16t*)Cout)[(size_t)(row + j) * N + col] = f2bf(v);
            }
        }
    }
}

// ---------------- k softmax stats (over n=4096) ----------------
// pass1: grid (64 bh, 16 chunks of 256 n), block 256: partial max/sum per (bh,chunk,d)
// two-pass in registers (64 vals/thread), fast exp
__global__ void k_softmax_p1(const u16t* __restrict__ qkv, float* __restrict__ pmax, float* __restrict__ psum) {
    int bh = blockIdx.x, chunk = blockIdx.y;
    int b = bh >> 4, h = bh & 15;
    int d = threadIdx.x & 63, sub = threadIdx.x >> 6;
    size_t base = (size_t)b * 4096 * 3072 + 1024 + h * 64 + d + (size_t)(chunk * 256 + sub) * 3072;
    float v[64];
#pragma unroll
    for (int i = 0; i < 64; i++)
        v[i] = bf2f(qkv[base + (size_t)i * 4 * 3072]);
    float m = v[0];
#pragma unroll
    for (int i = 1; i < 64; i++) m = fmaxf(m, v[i]);
    float s = 0.f;
#pragma unroll
    for (int i = 0; i < 64; i++) s += __expf(v[i] - m);
    __shared__ float sm[4][64], ss[4][64];
    sm[sub][d] = m; ss[sub][d] = s;
    __syncthreads();
    if (threadIdx.x < 64) {
        float M = sm[0][d];
        for (int i = 1; i < 4; i++) M = fmaxf(M, sm[i][d]);
        float S = 0.f;
        for (int i = 0; i < 4; i++) S += ss[i][d] * __expf(sm[i][d] - M);
        int o = (bh * 16 + chunk) * 64 + d;
        pmax[o] = M; psum[o] = S;
    }
}

// ---------------- context: ctxT[bh][e][d] = sum_n v[n][e] * ksoft[n][d] ----------------
// grid (64 bh, 8 chunks of 512 n), block 256. p2 (global stats combine) fused;
// k-softmax normalize fused into staging. 4 sub-chunks accumulated in reg -> 1 atomic pass.
__global__ __launch_bounds__(256) void context_kernel(const u16t* __restrict__ qkv,
                                                      const float* __restrict__ pmax, const float* __restrict__ psum,
                                                      float* __restrict__ ctxT) {
    int bh = blockIdx.x, chunk = blockIdx.y;
    int b = bh >> 4, h = bh & 15;
    __shared__ u16t kT[64][136];  // [d][n], pad to 136
    __shared__ u16t vT[64][136];  // [e][n]
    __shared__ float s_gm[64], s_gi[64];
    int t = threadIdx.x;
    if (t < 64) {
        float M = -1e30f;
        for (int c = 0; c < 16; c++) M = fmaxf(M, pmax[(bh * 16 + c) * 64 + t]);
        float S = 0.f;
        for (int c = 0; c < 16; c++) S += psum[(bh * 16 + c) * 64 + t] * __expf(pmax[(bh * 16 + c) * 64 + t] - M);
        s_gm[t] = M; s_gi[t] = 1.f / S;
    }
    __syncthreads();
    int d = t & 63, g = t >> 6;
    float gm = s_gm[d], gi = s_gi[d];
    int lane = t & 63, w = t >> 6;
    f32x4 acc[4] = {};
    for (int sub = 0; sub < 4; sub++) {
        size_t rowbase = ((size_t)b * 4096 + chunk * 512 + sub * 128) * 3072;
        for (int i = 0; i < 32; i++) {
            int n = g + i * 4;
            size_t ro = rowbase + (size_t)n * 3072 + h * 64 + d;
            kT[d][n] = f2bf(__expf(bf2f(qkv[ro + 1024]) - gm) * gi);
            vT[d][n] = qkv[ro + 2048];
        }
        __syncthreads();
#pragma unroll
        for (int ks = 0; ks < 4; ks++) {
            bf16x8 a = *(const bf16x8*)(&vT[w * 16 + (lane & 15)][ks * 32 + (lane >> 4) * 8]);
#pragma unroll
            for (int ct = 0; ct < 4; ct++) {
                bf16x8 bb = *(const bf16x8*)(&kT[ct * 16 + (lane & 15)][ks * 32 + (lane >> 4) * 8]);
                acc[ct] = __builtin_amdgcn_mfma_f32_16x16x32_bf16(a, bb, acc[ct], 0, 0, 0);
            }
        }
        __syncthreads();
    }
#pragma unroll
    for (int ct = 0; ct < 4; ct++) {
        int e = w * 16 + ((lane >> 4) << 2);
        int dd = ct * 16 + (lane & 15);
#pragma unroll
        for (int j = 0; j < 4; j++)
            atomicAdd(&ctxT[(size_t)bh * 4096 + (e + j) * 64 + dd], acc[ct][j]);
    }
}

// ---------------- attn GEMM (q-softmax fused): attn[n][h*64+e] = sum_d qsm[n][d] * ctxT[bh][e][d] ----
// grid (64 bh, 16 chunks of 256 n), block 256 (4 waves x 64 rows)
__global__ __launch_bounds__(256) void attn_gemm(const u16t* __restrict__ qkv, const float* __restrict__ ctxT,
                                                 u16t* __restrict__ attn) {
    int bh = blockIdx.x, chunk = blockIdx.y;
    int b = bh >> 4, h = bh & 15;
    __shared__ u16t q_lds[256][72];
    __shared__ u16t c_lds[64][72];
    int t = threadIdx.x;
#pragma unroll
    for (int i = 0; i < 16; i++) {
        int f = t + 256 * i;         // 0..4095
        int e = f >> 6, dd = f & 63;
        c_lds[e][dd] = f2bf(ctxT[(size_t)bh * 4096 + f]);
    }
    size_t qbase = ((size_t)b * 4096 + chunk * 256) * 3072 + h * 64;
#pragma unroll
    for (int i = 0; i < 8; i++) {
        int f = t + 256 * i;         // 0..2047 -> 256 rows x 8 quads
        int n = f >> 3, dg = f & 7;
        *(uint4*)(&q_lds[n][dg * 8]) = *(const uint4*)(&qkv[qbase + (size_t)n * 3072 + dg * 8]);
    }
    __syncthreads();
    // fused q softmax over d=64: one thread per row (256 threads = 256 rows)
    {
        ushort8 ch[8];
#pragma unroll
        for (int c = 0; c < 8; c++) ch[c] = *(const ushort8*)(&q_lds[t][c * 8]);
        float m = -1e30f;
#pragma unroll
        for (int c = 0; c < 8; c++)
#pragma unroll
            for (int j = 0; j < 8; j++) m = fmaxf(m, bf2f(ch[c][j]));
        float s = 0.f;
#pragma unroll
        for (int c = 0; c < 8; c++)
#pragma unroll
            for (int j = 0; j < 8; j++) s += __expf(bf2f(ch[c][j]) - m);
        float inv = 0.125f / s;   // fold SCALE
#pragma unroll
        for (int c = 0; c < 8; c++) {
            ushort8 o;
#pragma unroll
            for (int j = 0; j < 8; j++) o[j] = f2bf(__expf(bf2f(ch[c][j]) - m) * inv);
            *(ushort8*)(&q_lds[t][c * 8]) = o;
        }
    }
    __syncthreads();
    int lane = t & 63, w = t >> 6;
    f32x4 acc[4][4] = {};
#pragma unroll
    for (int ks = 0; ks < 2; ks++) {
        bf16x8 af[4], bfr[4];
#pragma unroll
        for (int mt = 0; mt < 4; mt++)
            af[mt] = *(const bf16x8*)(&q_lds[w * 64 + mt * 16 + (lane & 15)][ks * 32 + (lane >> 4) * 8]);
#pragma unroll
        for (int et = 0; et < 4; et++)
            bfr[et] = *(const bf16x8*)(&c_lds[et * 16 + (lane & 15)][ks * 32 + (lane >> 4) * 8]);
#pragma unroll
        for (int mt = 0; mt < 4; mt++)
#pragma unroll
            for (int et = 0; et < 4; et++)
                acc[mt][et] = __builtin_amdgcn_mfma_f32_16x16x32_bf16(af[mt], bfr[et], acc[mt][et], 0, 0, 0);
    }
    size_t abase = (size_t)b * 4096 + chunk * 256;
#pragma unroll
    for (int mt = 0; mt < 4; mt++) {
        int n = w * 64 + mt * 16 + ((lane >> 4) << 2);
#pragma unroll
        for (int et = 0; et < 4; et++) {
            int e = et * 16 + (lane & 15);
#pragma unroll
            for (int j = 0; j < 4; j++)
                attn[(abase + n + j) * 1024 + h * 64 + e] = f2bf(acc[mt][et][j]);
        }
    }
}

// ---------------- launch ----------------

extern "C" void kernel_launch(void* const* d_in, const int* in_sizes, int n_in,
                              void* d_out, int out_size, void* d_ws, size_t ws_size,
                              hipStream_t stream) {
    const float* x     = (const float*)d_in[0];
    const float* w_qkv = (const float*)d_in[1];
    const float* w_out = (const float*)d_in[2];
    const float* b_out = (const float*)d_in[3];
    float* out = (float*)d_out;
    char* ws = (char*)d_ws;

    // ws layout (bytes)
    size_t o_xb    = 0;                       // 16384*1024*2 = 33554432 (reused as attn)
    size_t o_wqkvT = 33554432;                // 3072*1024*2  = 6291456
    size_t o_woutT = 39845888;                // 1024*1024*2  = 2097152
    size_t o_qkv   = 41943040;                // 16384*3072*2 = 100663296
    size_t o_ctx   = 142606336;               // 64*64*64*4   = 1048576
    size_t o_pmax  = 143654912;               // 64*16*64*4   = 262144
    size_t o_psum  = 143917056;               // 262144
    size_t needed  = 144179200;
    if (ws_size < needed) return;             // visible failure if ws too small

    u16t* xb     = (u16t*)(ws + o_xb);
    u16t* attnb  = (u16t*)(ws + o_xb);        // reuse (xb dead after GEMM1)
    u16t* wqkvT  = (u16t*)(ws + o_wqkvT);
    u16t* woutT  = (u16t*)(ws + o_woutT);
    u16t* qkvb   = (u16t*)(ws + o_qkv);
    float* ctxT  = (float*)(ws + o_ctx);
    float* pmax  = (float*)(ws + o_pmax);
    float* psum  = (float*)(ws + o_psum);

    cvt_f32_bf16<<<2048, 256, 0, stream>>>(x, xb, 16777216);
    transpose_cvt<<<dim3(96, 32), dim3(32, 8), 0, stream>>>(w_qkv, wqkvT, 1024, 3072);
    transpose_cvt<<<dim3(32, 32), dim3(32, 8), 0, stream>>>(w_out, woutT, 1024, 1024);

    // GEMM1: [16384,1024] x [1024,3072] -> qkv ; grid 64*12 = 768 (div by 8)
    gemm256<0, 0><<<768, 512, 0, stream>>>(xb, wqkvT, qkvb, nullptr, 16384, 3072, 1024, 12);

    k_softmax_p1<<<dim3(64, 16), 256, 0, stream>>>(qkvb, pmax, psum);

    hipMemsetAsync(ctxT, 0, 64 * 64 * 64 * 4, stream);
    context_kernel<<<dim3(64, 8), 256, 0, stream>>>(qkvb, pmax, psum, ctxT);

    attn_gemm<<<dim3(64, 16), 256, 0, stream>>>(qkvb, ctxT, attnb);

    // GEMM2: [16384,1024] x [1024,1024] + bias -> out ; grid 64*4 = 256 (div by 8)
    gemm256<1, 1><<<256, 512, 0, stream>>>(attnb, woutT, out, b_out, 16384, 1024, 1024, 4);
}

// Round 8
// 220.080 us; speedup vs baseline: 1.0457x; 1.0457x over previous
//
#include <hip/hip_runtime.h>
#include <hip/hip_bf16.h>

// LinearAttention (efficient attention): B=4 N=4096 D_MODEL=1024 H=16 DH=64
// Pipeline: cvt -> GEMM1(qkv, 256^2 barrier-lite, q-softmax fused in epilogue)
//           -> ksoftmax stats -> context(K^T V, +p2 fused) -> W2 = ctx x w_out
//           -> final GEMM out = qsm x W2^T (+bias, f32). attn_gemm eliminated:
//           (qsm*ctx)*w_out == qsm*(ctx*w_out).

typedef unsigned short u16t;
typedef __bf16 bf16x8 __attribute__((ext_vector_type(8)));
typedef float f32x4 __attribute__((ext_vector_type(4)));
typedef unsigned short ushort8 __attribute__((ext_vector_type(8)));

__device__ __forceinline__ u16t f2bf(float f) {
    union { float f; unsigned int u; } v; v.f = f;
    unsigned int r = v.u + 0x7fffu + ((v.u >> 16) & 1u);
    return (u16t)(r >> 16);
}
__device__ __forceinline__ float bf2f(u16t h) {
    union { unsigned int u; float f; } v; v.u = ((unsigned int)h) << 16;
    return v.f;
}

#define GLOAD_LDS16(gptr, lptr) \
    __builtin_amdgcn_global_load_lds((const __attribute__((address_space(1))) unsigned int*)(gptr), \
                                     (__attribute__((address_space(3))) unsigned int*)(lptr), 16, 0, 0)
#define SFENCE asm volatile("" ::: "memory")

// ---------------- conversion kernels ----------------

__global__ void cvt_f32_bf16(const float* __restrict__ in, u16t* __restrict__ out, int n) {
    int i = (blockIdx.x * blockDim.x + threadIdx.x) * 4;
    int stride = gridDim.x * blockDim.x * 4;
    for (; i < n; i += stride) {
        float4 v = *(const float4*)(in + i);
        ushort4 o;
        o.x = f2bf(v.x); o.y = f2bf(v.y); o.z = f2bf(v.z); o.w = f2bf(v.w);
        *(ushort4*)(out + i) = o;
    }
}

// in [R][C] f32 -> out [C][R] bf16 (transpose + convert). grid (C/32, R/32), block (32,8)
__global__ void transpose_cvt(const float* __restrict__ in, u16t* __restrict__ out, int R, int C) {
    __shared__ float tile[32][33];
    int c0 = blockIdx.x * 32, r0 = blockIdx.y * 32;
    int tx = threadIdx.x, ty = threadIdx.y;
    for (int i = 0; i < 32; i += 8)
        tile[ty + i][tx] = in[(size_t)(r0 + ty + i) * C + c0 + tx];
    __syncthreads();
    for (int i = 0; i < 32; i += 8)
        out[(size_t)(c0 + ty + i) * R + r0 + tx] = f2bf(tile[tx][ty + i]);
}

// ---------------- 256x256 barrier-lite bf16 GEMM: C = A * Bt^T ----------------
// A [M][lda] bf16 row-major (cols 0..K-1 used), Bt [N][K] bf16 row-major.
// 512 threads = 8 waves (2 M x 4 N), per-wave output 128x64, BK=64, LDS 128KB dbuf.
// r6 barrier-lite schedule (best of r3-r7): 2 barriers/K-tile, counted vmcnt,
// no lgkm pins. T2 swizzle verified conflict-free (r3). XCD-bijective grid swizzle.
// QSM: for q-column blocks (n0+wn*64 < 1024), apply per-row softmax over the wave's
// 64 cols (= one head) on f32 acc before store: 4-step shfl_xor butterfly x16 lanes.
// BATCHB: Bt += (by>>4)*2^20 (per-batch W2T for the final GEMM).
template<int OUTF32, int BIAS, int QSM, int BATCHB>
__global__ __launch_bounds__(512, 2) void gemm256(const u16t* __restrict__ A, const u16t* __restrict__ Bt,
                                                  void* __restrict__ Cout, const float* __restrict__ bias,
                                                  int M, int N, int K, int NBX, int lda) {
    __shared__ __align__(16) u16t lds[65536];   // 128 KB
    const int t = threadIdx.x;
    const int l = t & 63, w = t >> 6;
    const int wm = w >> 2, wn = w & 3;

    // XCD-aware bijective swizzle (gridDim.x % 8 == 0)
    int cpx = gridDim.x >> 3;
    int wg = ((int)blockIdx.x & 7) * cpx + ((int)blockIdx.x >> 3);
    int bx = wg % NBX, by = wg / NBX;
    const int m0 = by * 256, n0 = bx * 256;
    const int NT = K >> 6;
    if (BATCHB) Bt += (size_t)(by >> 4) << 20;

    // fragment read addressing (u16 units, swizzle folded)
    const int colk0 = ((l >> 4) ^ (l & 7)) * 8;
    const int colk1 = colk0 ^ 32;
    const int abase = (wm * 32 + (l & 15)) * 64;                       // within A group
    const int bbase = 16384 + (wn >> 1) * 8192 + ((wn & 1) * 64 + (l & 15)) * 64;

    // staging addressing
    const int rr = w * 8 + (l >> 3);                                   // row within 64-row group
    const int coloff = ((l ^ (l >> 3)) & 7) * 8;                       // inverse swizzle on source
    const int rowA = rr + ((rr >= 32) ? 96 : 0);                       // A group-local -> global offset
    const u16t* pa_st = A  + (size_t)(m0 + rowA) * lda + coloff;
    const u16t* pb_st = Bt + (size_t)(n0 + rr) * K + coloff;
    const int so = w * 512;

#define SPAIR(qq, kto, pb) do { \
    size_t k64_ = (size_t)(kto) * 64; \
    if ((qq) == 0) { \
        GLOAD_LDS16(pb_st + k64_,                  &lds[(pb) * 32768 + 16384 + so]); \
        GLOAD_LDS16(pb_st + k64_ + (size_t)64 * K, &lds[(pb) * 32768 + 20480 + so]); \
    } else if ((qq) == 1) { \
        GLOAD_LDS16(pb_st + k64_ + (size_t)128 * K, &lds[(pb) * 32768 + 24576 + so]); \
        GLOAD_LDS16(pb_st + k64_ + (size_t)192 * K, &lds[(pb) * 32768 + 28672 + so]); \
    } else if ((qq) == 2) { \
        GLOAD_LDS16(pa_st + k64_,                    &lds[(pb) * 32768 + so]); \
        GLOAD_LDS16(pa_st + k64_ + (size_t)32 * lda, &lds[(pb) * 32768 + 4096 + so]); \
    } else { \
        GLOAD_LDS16(pa_st + k64_ + (size_t)64 * lda, &lds[(pb) * 32768 + 8192 + so]); \
        GLOAD_LDS16(pa_st + k64_ + (size_t)96 * lda, &lds[(pb) * 32768 + 12288 + so]); \
    } \
} while (0)

    f32x4 acc[8][4] = {};

    // prologue: stage tile 0 -> buf 0. Fence keeps S3 youngest so counted waits
    // identify whole groups.
    SPAIR(0, 0, 0); SPAIR(1, 0, 0); SPAIR(2, 0, 0);
    SFENCE;
    SPAIR(3, 0, 0);

    for (int kt = 0; kt < NT; ++kt) {
        const int p = kt & 1;
        const bool sn = (kt + 1 < NT);
        const u16t* lA = &lds[p * 32768];

        // ---- entry: B + A-g01 of this tile landed ----
        asm volatile("s_waitcnt vmcnt(2)" ::: "memory");
        __builtin_amdgcn_s_barrier();

        // ---- window 1: B frags + A groups 0,1 ; stage S0,S1,S2 ; 32 MFMA ----
        bf16x8 bfr[4][2];
#pragma unroll
        for (int ni = 0; ni < 4; ++ni) {
            bfr[ni][0] = *(const bf16x8*)&lA[bbase + ni * 1024 + colk0];
            bfr[ni][1] = *(const bf16x8*)&lA[bbase + ni * 1024 + colk1];
        }
        bf16x8 af1[2][2][2];  // [g][dm][kk], groups 0,1
#pragma unroll
        for (int g = 0; g < 2; ++g) {
            af1[g][0][0] = *(const bf16x8*)&lA[g * 4096 + abase + colk0];
            af1[g][0][1] = *(const bf16x8*)&lA[g * 4096 + abase + colk1];
            af1[g][1][0] = *(const bf16x8*)&lA[g * 4096 + abase + 1024 + colk0];
            af1[g][1][1] = *(const bf16x8*)&lA[g * 4096 + abase + 1024 + colk1];
        }
        if (sn) { SPAIR(0, kt + 1, p ^ 1); SPAIR(1, kt + 1, p ^ 1); SPAIR(2, kt + 1, p ^ 1); }
        __builtin_amdgcn_s_setprio(1);
#pragma unroll
        for (int g = 0; g < 2; ++g)
#pragma unroll
            for (int dm = 0; dm < 2; ++dm)
#pragma unroll
                for (int ni = 0; ni < 4; ++ni)
#pragma unroll
                    for (int kk = 0; kk < 2; ++kk)
                        acc[g * 2 + dm][ni] = __builtin_amdgcn_mfma_f32_16x16x32_bf16(
                            af1[g][dm][kk], bfr[ni][kk], acc[g * 2 + dm][ni], 0, 0, 0);
        __builtin_amdgcn_s_setprio(0);

        // ---- mid: A-g23 of this tile landed ----
        if (sn) asm volatile("s_waitcnt vmcnt(6)" ::: "memory");
        else    asm volatile("s_waitcnt vmcnt(0)" ::: "memory");
        __builtin_amdgcn_s_barrier();

        // ---- window 2: A groups 2,3 ; stage S3 ; 32 MFMA ----
        bf16x8 af2[2][2][2];  // groups 2,3
#pragma unroll
        for (int g = 0; g < 2; ++g) {
            af2[g][0][0] = *(const bf16x8*)&lA[(g + 2) * 4096 + abase + colk0];
            af2[g][0][1] = *(const bf16x8*)&lA[(g + 2) * 4096 + abase + colk1];
            af2[g][1][0] = *(const bf16x8*)&lA[(g + 2) * 4096 + abase + 1024 + colk0];
            af2[g][1][1] = *(const bf16x8*)&lA[(g + 2) * 4096 + abase + 1024 + colk1];
        }
        if (sn) SPAIR(3, kt + 1, p ^ 1);
        __builtin_amdgcn_s_setprio(1);
#pragma unroll
        for (int g = 0; g < 2; ++g)
#pragma unroll
            for (int dm = 0; dm < 2; ++dm)
#pragma unroll
                for (int ni = 0; ni < 4; ++ni)
#pragma unroll
                    for (int kk = 0; kk < 2; ++kk)
                        acc[4 + g * 2 + dm][ni] = __builtin_amdgcn_mfma_f32_16x16x32_bf16(
                            af2[g][dm][kk], bfr[ni][kk], acc[4 + g * 2 + dm][ni], 0, 0, 0);
        __builtin_amdgcn_s_setprio(0);
    }
#undef SPAIR

    // ---- fused q-softmax over d=64 (wave's 64 cols = one head), f32 acc ----
    if (QSM && (n0 + wn * 64 < 1024)) {
#pragma unroll
        for (int mi = 0; mi < 8; ++mi)
#pragma unroll
            for (int jj = 0; jj < 4; ++jj) {
                float v0 = acc[mi][0][jj], v1 = acc[mi][1][jj];
                float v2 = acc[mi][2][jj], v3 = acc[mi][3][jj];
                float m = fmaxf(fmaxf(v0, v1), fmaxf(v2, v3));
#pragma unroll
                for (int o = 1; o < 16; o <<= 1) m = fmaxf(m, __shfl_xor(m, o));
                float e0 = __expf(v0 - m), e1 = __expf(v1 - m);
                float e2 = __expf(v2 - m), e3 = __expf(v3 - m);
                float s = e0 + e1 + e2 + e3;
#pragma unroll
                for (int o = 1; o < 16; o <<= 1) s += __shfl_xor(s, o);
                float inv = 0.125f / s;   // fold SCALE
                acc[mi][0][jj] = e0 * inv; acc[mi][1][jj] = e1 * inv;
                acc[mi][2][jj] = e2 * inv; acc[mi][3][jj] = e3 * inv;
            }
    }

    // epilogue
#pragma unroll
    for (int mi = 0; mi < 8; ++mi) {
        int row = m0 + wm * 128 + mi * 16 + ((l >> 4) << 2);
#pragma unroll
        for (int ni = 0; ni < 4; ++ni) {
            int col = n0 + wn * 64 + ni * 16 + (l & 15);
            float bv = BIAS ? bias[col] : 0.f;
#pragma unroll
            for (int j = 0; j < 4; ++j) {
                float v = acc[mi][ni][j] + bv;
                if (OUTF32) ((float*)Cout)[(size_t)(row + j) * N + col] = v;
                else        ((u16t*)Cout)[(size_t)(row + j) * N + col] = f2bf(v);
            }
        }
    }
}

// ---------------- k softmax stats (over n=4096) ----------------
// pass1: grid (64 bh, 16 chunks of 256 n), block 256: partial max/sum per (bh,chunk,d)
__global__ void k_softmax_p1(const u16t* __restrict__ qkv, float* __restrict__ pmax, float* __restrict__ psum) {
    int bh = blockIdx.x, chunk = blockIdx.y;
    int b = bh >> 4, h = bh & 15;
    int d = threadIdx.x & 63, sub = threadIdx.x >> 6;
    size_t base = (size_t)b * 4096 * 3072 + 1024 + h * 64 + d + (size_t)(chunk * 256 + sub) * 3072;
    float v[64];
#pragma unroll
    for (int i = 0; i < 64; i++)
        v[i] = bf2f(qkv[base + (size_t)i * 4 * 3072]);
    float m = v[0];
#pragma unroll
    for (int i = 1; i < 64; i++) m = fmaxf(m, v[i]);
    float s = 0.f;
#pragma unroll
    for (int i = 0; i < 64; i++) s += __expf(v[i] - m);
    __shared__ float sm[4][64], ss[4][64];
    sm[sub][d] = m; ss[sub][d] = s;
    __syncthreads();
    if (threadIdx.x < 64) {
        float M = sm[0][d];
        for (int i = 1; i < 4; i++) M = fmaxf(M, sm[i][d]);
        float S = 0.f;
        for (int i = 0; i < 4; i++) S += ss[i][d] * __expf(sm[i][d] - M);
        int o = (bh * 16 + chunk) * 64 + d;
        pmax[o] = M; psum[o] = S;
    }
}

// ---------------- context: ctxT[bh][e][d] = sum_n v[n][e] * ksoft[n][d] ----------------
// grid (64 bh, 8 chunks of 512 n), block 256. p2 (global stats combine) fused;
// k-softmax normalize fused into staging. 4 sub-chunks accumulated in reg -> 1 atomic pass.
__global__ __launch_bounds__(256) void context_kernel(const u16t* __restrict__ qkv,
                                                      const float* __restrict__ pmax, const float* __restrict__ psum,
                                                      float* __restrict__ ctxT) {
    int bh = blockIdx.x, chunk = blockIdx.y;
    int b = bh >> 4, h = bh & 15;
    __shared__ u16t kT[64][136];  // [d][n], pad to 136
    __shared__ u16t vT[64][136];  // [e][n]
    __shared__ float s_gm[64], s_gi[64];
    int t = threadIdx.x;
    if (t < 64) {
        float M = -1e30f;
        for (int c = 0; c < 16; c++) M = fmaxf(M, pmax[(bh * 16 + c) * 64 + t]);
        float S = 0.f;
        for (int c = 0; c < 16; c++) S += psum[(bh * 16 + c) * 64 + t] * __expf(pmax[(bh * 16 + c) * 64 + t] - M);
        s_gm[t] = M; s_gi[t] = 1.f / S;
    }
    __syncthreads();
    int d = t & 63, g = t >> 6;
    float gm = s_gm[d], gi = s_gi[d];
    int lane = t & 63, w = t >> 6;
    f32x4 acc[4] = {};
    for (int sub = 0; sub < 4; sub++) {
        size_t rowbase = ((size_t)b * 4096 + chunk * 512 + sub * 128) * 3072;
        for (int i = 0; i < 32; i++) {
            int n = g + i * 4;
            size_t ro = rowbase + (size_t)n * 3072 + h * 64 + d;
            kT[d][n] = f2bf(__expf(bf2f(qkv[ro + 1024]) - gm) * gi);
            vT[d][n] = qkv[ro + 2048];
        }
        __syncthreads();
#pragma unroll
        for (int ks = 0; ks < 4; ks++) {
            bf16x8 a = *(const bf16x8*)(&vT[w * 16 + (lane & 15)][ks * 32 + (lane >> 4) * 8]);
#pragma unroll
            for (int ct = 0; ct < 4; ct++) {
                bf16x8 bb = *(const bf16x8*)(&kT[ct * 16 + (lane & 15)][ks * 32 + (lane >> 4) * 8]);
                acc[ct] = __builtin_amdgcn_mfma_f32_16x16x32_bf16(a, bb, acc[ct], 0, 0, 0);
            }
        }
        __syncthreads();
    }
#pragma unroll
    for (int ct = 0; ct < 4; ct++) {
        int e = w * 16 + ((lane >> 4) << 2);
        int dd = ct * 16 + (lane & 15);
#pragma unroll
        for (int j = 0; j < 4; j++)
            atomicAdd(&ctxT[(size_t)bh * 4096 + (e + j) * 64 + dd], acc[ct][j]);
    }
}

// ---------------- W2: W2T[b][j][h*64+d] = sum_e ctxT[bh][e][d] * woutT[j][h*64+e] ----
// grid (64 bh, 4 jc of 256), block 256 (4 waves: wave w -> j rows w*64..w*64+63)
__global__ __launch_bounds__(256) void w2_kernel(const float* __restrict__ ctxT,
                                                 const u16t* __restrict__ woutT,
                                                 u16t* __restrict__ w2t) {
    int bh = blockIdx.x, jc = blockIdx.y;
    int b = bh >> 4, h = bh & 15;
    __shared__ u16t cb[64][72];    // [d][e] bf16 (transposed ctx)
    __shared__ u16t wl[256][72];   // [j][e] (64 cols used, pad 72 vs bank conflict)
    int t = threadIdx.x;
#pragma unroll
    for (int i = 0; i < 16; i++) {
        int f = t + 256 * i;       // f = e*64+d
        cb[f & 63][f >> 6] = f2bf(ctxT[(size_t)bh * 4096 + f]);
    }
#pragma unroll
    for (int i = 0; i < 8; i++) {
        int f = t + 256 * i;       // r = f>>3 (0..255), q = f&7
        int r = f >> 3, q = f & 7;
        *(uint4*)(&wl[r][q * 8]) = *(const uint4*)(&woutT[(size_t)(jc * 256 + r) * 1024 + h * 64 + q * 8]);
    }
    __syncthreads();
    int l = t & 63, w = t >> 6;
    f32x4 acc[4][4] = {};
#pragma unroll
    for (int kk = 0; kk < 2; kk++) {
        bf16x8 af[4], bfr[4];
#pragma unroll
        for (int mt = 0; mt < 4; mt++)
            af[mt] = *(const bf16x8*)&wl[w * 64 + mt * 16 + (l & 15)][(l >> 4) * 8 + kk * 32];
#pragma unroll
        for (int nt = 0; nt < 4; nt++)
            bfr[nt] = *(const bf16x8*)&cb[nt * 16 + (l & 15)][(l >> 4) * 8 + kk * 32];
#pragma unroll
        for (int mt = 0; mt < 4; mt++)
#pragma unroll
            for (int nt = 0; nt < 4; nt++)
                acc[mt][nt] = __builtin_amdgcn_mfma_f32_16x16x32_bf16(af[mt], bfr[nt], acc[mt][nt], 0, 0, 0);
    }
#pragma unroll
    for (int mt = 0; mt < 4; mt++) {
        int j = jc * 256 + w * 64 + mt * 16 + ((l >> 4) << 2);
#pragma unroll
        for (int nt = 0; nt < 4; nt++) {
            int dd = nt * 16 + (l & 15);
#pragma unroll
            for (int jj = 0; jj < 4; jj++)
                w2t[((size_t)b << 20) + (size_t)(j + jj) * 1024 + h * 64 + dd] = f2bf(acc[mt][nt][jj]);
        }
    }
}

// ---------------- launch ----------------

extern "C" void kernel_launch(void* const* d_in, const int* in_sizes, int n_in,
                              void* d_out, int out_size, void* d_ws, size_t ws_size,
                              hipStream_t stream) {
    const float* x     = (const float*)d_in[0];
    const float* w_qkv = (const float*)d_in[1];
    const float* w_out = (const float*)d_in[2];
    const float* b_out = (const float*)d_in[3];
    float* out = (float*)d_out;
    char* ws = (char*)d_ws;

    // ws layout (bytes)
    size_t o_xb    = 0;                       // 16384*1024*2 = 33554432 (reused as w2t)
    size_t o_wqkvT = 33554432;                // 3072*1024*2  = 6291456
    size_t o_woutT = 39845888;                // 1024*1024*2  = 2097152
    size_t o_qkv   = 41943040;                // 16384*3072*2 = 100663296
    size_t o_ctx   = 142606336;               // 64*64*64*4   = 1048576
    size_t o_pmax  = 143654912;               // 64*16*64*4   = 262144
    size_t o_psum  = 143917056;               // 262144
    size_t needed  = 144179200;
    if (ws_size < needed) return;             // visible failure if ws too small

    u16t* xb     = (u16t*)(ws + o_xb);
    u16t* w2t    = (u16t*)(ws + o_xb);        // reuse (xb dead after GEMM1); 4*1024*1024*2 = 8MB
    u16t* wqkvT  = (u16t*)(ws + o_wqkvT);
    u16t* woutT  = (u16t*)(ws + o_woutT);
    u16t* qkvb   = (u16t*)(ws + o_qkv);
    float* ctxT  = (float*)(ws + o_ctx);
    float* pmax  = (float*)(ws + o_pmax);
    float* psum  = (float*)(ws + o_psum);

    cvt_f32_bf16<<<2048, 256, 0, stream>>>(x, xb, 16777216);
    transpose_cvt<<<dim3(96, 32), dim3(32, 8), 0, stream>>>(w_qkv, wqkvT, 1024, 3072);
    transpose_cvt<<<dim3(32, 32), dim3(32, 8), 0, stream>>>(w_out, woutT, 1024, 1024);

    // GEMM1: [16384,1024] x [1024,3072] -> qkv (q cols softmaxed in epilogue)
    gemm256<0, 0, 1, 0><<<768, 512, 0, stream>>>(xb, wqkvT, qkvb, nullptr, 16384, 3072, 1024, 12, 1024);

    k_softmax_p1<<<dim3(64, 16), 256, 0, stream>>>(qkvb, pmax, psum);

    hipMemsetAsync(ctxT, 0, 64 * 64 * 64 * 4, stream);
    context_kernel<<<dim3(64, 8), 256, 0, stream>>>(qkvb, pmax, psum, ctxT);

    // W2T[b][j][hd] = sum_e ctx[bh][e][d] * w_out[he][j]
    w2_kernel<<<dim3(64, 4), 256, 0, stream>>>(ctxT, woutT, w2t);

    // final GEMM: out[b] = qsm[b] (lda=3072, cols 0..1023) x W2T[b]^T + bias ; f32 out
    gemm256<1, 1, 0, 1><<<256, 512, 0, stream>>>(qkvb, w2t, out, b_out, 16384, 1024, 1024, 4, 3072);
}